// Round 7
// baseline (211.680 us; speedup 1.0000x reference)
//
#include <hip/hip_runtime.h>

#define LOG2E 1.4426950408889634f
#define BN_EPS 1e-5f

// ws float offsets
#define WS_BN1S  0      // sc1[18]
#define WS_BN1H  18     // sh1[18]
#define WS_BN2S  36     // sc2[9]
#define WS_BN2H  45     // sh2[9]
#define WS_L1    64     // per dir (stride 32): w[8], u[16], b[8]  (pre-scaled)
#define WS_L2    128    // per dir (stride 24): W[16], U[4], b[4]  (pre-scaled)
#define WS_PART1 1024   // k_moments partials: [nbp][64] (54 used)
#define WS_PART2 66560  // k_stats2 partials:  [nbp][32] (18 used)
#define WS_Z2    131072 // z2 cache, col-major [9][B]

__device__ __forceinline__ float relu_(float x){ return fmaxf(x, 0.f); }

__device__ __forceinline__ float wsum(float v){
    #pragma unroll
    for (int m = 32; m >= 1; m >>= 1) v += __shfl_xor(v, m, 64);
    return v;
}

__device__ constexpr int TRI(int j, int l){ return j*9 - j*(j-1)/2 + (l - j); }

__device__ __forceinline__ void load_h0(const float* __restrict__ x, const float* __restrict__ emb,
                                        long row, float h0[9])
{
    const float4* xv = (const float4*)(x + row * 8);
    float4 p = xv[0];
    float4 q = xv[1];
    int idx = (int)p.x;
    float2 e = ((const float2*)emb)[idx];
    h0[0] = e.x; h0[1] = e.y;
    h0[2] = p.y; h0[3] = p.z; h0[4] = p.w;
    h0[5] = q.x; h0[6] = q.y; h0[7] = q.z; h0[8] = q.w;
}

// LSTM cell, pre-scaled z's: zi,zo scaled +log2e; zf scaled -log2e; zg scaled +2*log2e.
// Shared rcp across i/f/g: 5 exp2 + 2 rcp.
__device__ __forceinline__ float cellh(float zi, float zfn, float zg2, float zo, float& c){
    float A  = __builtin_amdgcn_exp2f(zi);
    float G  = __builtin_amdgcn_exp2f(zg2);
    float Fp = __builtin_amdgcn_exp2f(zfn);
    float pA = 1.f + A, pG = 1.f + G, pF = 1.f + Fp;
    float pAG = pA * pG;
    float R  = __builtin_amdgcn_rcpf(pAG * pF);
    float icg = A * (G - 1.f) * pF * R;   // sig(i)*tanh(g)
    float fs  = pAG * R;                  // sig(f)
    c = fmaf(fs, c, icg);
    float O  = __builtin_amdgcn_exp2f(zo);
    float T  = __builtin_amdgcn_exp2f((2.f * LOG2E) * c);
    return O * (T - 1.f) * __builtin_amdgcn_rcpf((1.f + O) * (1.f + T));  // sig(o)*tanh(c)
}

struct KParams {
    const float *x, *emb, *W1, *b1, *g1, *be1, *W2, *b2, *g2, *be2;
    const float *w1f, *u1f, *c1f, *w1r, *u1r, *c1r;
    const float *w2f, *u2f, *c2f, *w2r, *u2r, *c2r;
    float* ws;
    float* out;
    int B;
    int nbp;   // partial-block count (grid of k_moments / k_stats2)
};

// ============ K1: h0 moments -> per-block partials (no atomics) ============
__global__ __launch_bounds__(256) void k_moments(const float* __restrict__ x, const float* __restrict__ emb,
                                                 float* __restrict__ part1, int B)
{
    const int tid = threadIdx.x;
    float s9[9], mt[45];
    #pragma unroll
    for (int j = 0; j < 9; ++j) s9[j] = 0.f;
    #pragma unroll
    for (int t = 0; t < 45; ++t) mt[t] = 0.f;

    const long sweep = (long)gridDim.x * 1024;
    for (long b0 = (long)blockIdx.x * 1024; b0 < B; b0 += sweep){
        #pragma unroll
        for (int r = 0; r < 4; ++r){
            long row = b0 + tid + r * 256;
            if (row < B){
                float h0[9];
                load_h0(x, emb, row, h0);
                #pragma unroll
                for (int j = 0; j < 9; ++j){
                    s9[j] += h0[j];
                    #pragma unroll
                    for (int l = j; l < 9; ++l)
                        mt[TRI(j,l)] = fmaf(h0[j], h0[l], mt[TRI(j,l)]);
                }
            }
        }
    }
    __shared__ float sm[54];
    if (tid < 54) sm[tid] = 0.f;
    __syncthreads();
    bool l0 = (tid & 63) == 0;
    #pragma unroll
    for (int j = 0; j < 9; ++j){
        float v = wsum(s9[j]);
        if (l0) atomicAdd(&sm[j], v);
    }
    #pragma unroll
    for (int t = 0; t < 45; ++t){
        float v = wsum(mt[t]);
        if (l0) atomicAdd(&sm[9 + t], v);
    }
    __syncthreads();
    if (tid < 54)      part1[(long)blockIdx.x * 64 + tid] = sm[tid];
    else if (tid < 64) part1[(long)blockIdx.x * 64 + tid] = 0.f;
}

// ============ kRed1: reduce partials -> BN1 consts ============
__global__ __launch_bounds__(1024) void kRed1(KParams p)
{
    const int tid = threadIdx.x;
    const float* part1 = p.ws + WS_PART1;
    __shared__ float red[16][64];
    int c = tid & 63, seg = tid >> 6;
    float s = 0.f;
    #pragma unroll 4
    for (int i = 0; i < 64; ++i){
        int b = seg * 64 + i;
        if (b < p.nbp) s += part1[(long)b * 64 + c];
    }
    red[seg][c] = s;
    __syncthreads();
    if (seg == 0){
        float tot = 0.f;
        #pragma unroll
        for (int q = 0; q < 16; ++q) tot += red[q][c];
        red[0][c] = tot;
    }
    __syncthreads();
    if (tid < 18){
        const float invB = 1.f / (float)p.B;
        int k = tid;
        float w[9];
        #pragma unroll
        for (int j = 0; j < 9; ++j) w[j] = p.W1[k*9 + j];
        float dot9 = 0.f, q = 0.f;
        #pragma unroll
        for (int j = 0; j < 9; ++j){
            dot9 = fmaf(w[j], red[0][j], dot9);
            q = fmaf(w[j]*w[j], red[0][9 + TRI(j,j)], q);
            #pragma unroll
            for (int l = j+1; l < 9; ++l)
                q = fmaf(2.f*w[j]*w[l], red[0][9 + TRI(j,l)], q);
        }
        float m1  = dot9 * invB;
        float var = fmaf(-m1, m1, q * invB);
        float mu  = m1 + p.b1[k];
        float sc  = p.g1[k] * __builtin_amdgcn_rsqf(var + BN_EPS);
        p.ws[WS_BN1S + k] = sc;
        p.ws[WS_BN1H + k] = fmaf(-mu, sc, p.be1[k]);
    }
}

// ============ K2: BN1 -> z2 store + z2 partial stats (no atomics) ============
template<int STORE_Z2>
__global__ __launch_bounds__(256) void k_stats2(KParams p)
{
    const int tid = threadIdx.x;
    float sc1[18], sh1[18];
    #pragma unroll
    for (int k = 0; k < 18; ++k){
        sc1[k] = p.ws[WS_BN1S + k];
        sh1[k] = p.ws[WS_BN1H + k];
    }

    float as[9], aq[9];
    #pragma unroll
    for (int k = 0; k < 9; ++k){ as[k] = 0.f; aq[k] = 0.f; }

    float* z2buf = p.ws + WS_Z2;
    const long sweep = (long)gridDim.x * 1024;
    for (long b0 = (long)blockIdx.x * 1024; b0 < p.B; b0 += sweep){
        #pragma unroll
        for (int r = 0; r < 4; ++r){
            long row = b0 + tid + r * 256;
            if (row < p.B){
                float h0[9];
                load_h0(p.x, p.emb, row, h0);
                float a1[18];
                #pragma unroll
                for (int k = 0; k < 18; ++k){
                    float s = p.b1[k];
                    #pragma unroll
                    for (int j = 0; j < 9; ++j) s = fmaf(p.W1[k*9 + j], h0[j], s);
                    a1[k] = relu_(fmaf(sc1[k], s, sh1[k]));
                }
                #pragma unroll
                for (int k = 0; k < 9; ++k){
                    float s = p.b2[k];
                    #pragma unroll
                    for (int j = 0; j < 18; ++j) s = fmaf(p.W2[k*18 + j], a1[j], s);
                    if (STORE_Z2) z2buf[(long)k * p.B + row] = s;
                    as[k] += s; aq[k] = fmaf(s, s, aq[k]);
                }
            }
        }
    }
    __shared__ float sm2[18];
    if (tid < 18) sm2[tid] = 0.f;
    __syncthreads();
    bool l0 = (tid & 63) == 0;
    #pragma unroll
    for (int k = 0; k < 9; ++k){
        float s = wsum(as[k]);
        float q = wsum(aq[k]);
        if (l0){ atomicAdd(&sm2[k], s); atomicAdd(&sm2[9 + k], q); }
    }
    __syncthreads();
    float* part2 = p.ws + WS_PART2;
    if (tid < 18)      part2[(long)blockIdx.x * 32 + tid] = sm2[tid];
    else if (tid < 32) part2[(long)blockIdx.x * 32 + tid] = 0.f;
}

// ============ kPrep: reduce z2 partials -> BN2 consts; pre-scale LSTM weights ============
__global__ __launch_bounds__(256) void kPrep(KParams p)
{
    const int tid = threadIdx.x;
    float* ws = p.ws;
    const float scl[4] = { LOG2E, -LOG2E, 2.f*LOG2E, LOG2E };  // i, f, g, o

    __shared__ float red[8][32];
    {
        const float* part2 = ws + WS_PART2;
        int c = tid & 31, seg = tid >> 5;
        float s = 0.f;
        #pragma unroll 4
        for (int i = 0; i < 128; ++i){
            int b = seg * 128 + i;
            if (b < p.nbp) s += part2[(long)b * 32 + c];
        }
        red[seg][c] = s;
    }
    __syncthreads();
    if (tid < 32){
        float tot = 0.f;
        #pragma unroll
        for (int q = 0; q < 8; ++q) tot += red[q][tid];
        red[0][tid] = tot;
    }
    __syncthreads();

    if (tid < 9){
        const float invB = 1.f / (float)p.B;
        int k = tid;
        float mu  = red[0][k] * invB;
        float var = fmaf(-mu, mu, red[0][9 + k] * invB);
        float sc  = p.g2[k] * __builtin_amdgcn_rsqf(var + BN_EPS);
        ws[WS_BN2S + k] = sc;
        ws[WS_BN2H + k] = fmaf(-mu, sc, p.be2[k]);
    } else if (tid >= 32 && tid < 48){
        int r = tid - 32;
        int dir = r >> 3, rr = r & 7;
        const float* W = dir ? p.w1r : p.w1f;
        const float* U = dir ? p.u1r : p.u1f;
        const float* Bb = dir ? p.c1r : p.c1f;
        float sc = scl[rr >> 1];
        float* dst = ws + WS_L1 + dir * 32;
        dst[rr]            = sc * W[rr];
        dst[8 + 2*rr]      = sc * U[2*rr];
        dst[8 + 2*rr + 1]  = sc * U[2*rr + 1];
        dst[24 + rr]       = sc * Bb[rr];
    } else if (tid >= 48 && tid < 56){
        int r = tid - 48;
        int dir = r >> 2, rr = r & 3;
        const float* W = dir ? p.w2r : p.w2f;
        const float* U = dir ? p.u2r : p.u2f;
        const float* Bb = dir ? p.c2r : p.c2f;
        float sc = scl[rr];
        float* dst = ws + WS_L2 + dir * 24;
        #pragma unroll
        for (int j = 0; j < 4; ++j) dst[4*rr + j] = sc * W[4*rr + j];
        dst[16 + rr] = sc * U[rr];
        dst[20 + rr] = sc * Bb[rr];
    }
}

// ============ kB: BN2 + biLSTM x2 + output ============
template<int USE_WS>
__global__ __launch_bounds__(256) void kB(KParams p)
{
    const int tid = threadIdx.x;
    const float* ws = p.ws;
    const float* z2buf = ws + WS_Z2;
    const float* L1F = ws + WS_L1;          // w[8], u[16], b[8]
    const float* L1R = ws + WS_L1 + 32;
    const float* L2F = ws + WS_L2;          // W[16], U[4], b[4]
    const float* L2R = ws + WS_L2 + 24;

    long row = (long)blockIdx.x * 256 + tid;
    if (row >= p.B) return;

    // ---- a2 = relu(BN2(z2)) ----
    float a2[9];
    if (USE_WS){
        #pragma unroll
        for (int k = 0; k < 9; ++k){
            float z = z2buf[(long)k * p.B + row];
            a2[k] = relu_(fmaf(ws[WS_BN2S + k], z, ws[WS_BN2H + k]));
        }
    } else {
        float h0[9];
        load_h0(p.x, p.emb, row, h0);
        float a1[18];
        #pragma unroll
        for (int k = 0; k < 18; ++k){
            float s = p.b1[k];
            #pragma unroll
            for (int j = 0; j < 9; ++j) s = fmaf(p.W1[k*9 + j], h0[j], s);
            a1[k] = relu_(fmaf(ws[WS_BN1S + k], s, ws[WS_BN1H + k]));
        }
        #pragma unroll
        for (int k = 0; k < 9; ++k){
            float s = p.b2[k];
            #pragma unroll
            for (int j = 0; j < 18; ++j) s = fmaf(p.W2[k*18 + j], a1[j], s);
            a2[k] = relu_(fmaf(ws[WS_BN2S + k], s, ws[WS_BN2H + k]));
        }
    }

    // ---- biLSTM layer 1 (scalar, both dirs) ----
    float hf0 = 0.f, hf1 = 0.f, cf0 = 0.f, cf1 = 0.f;
    float hr0 = 0.f, hr1 = 0.f, cr0 = 0.f, cr1 = 0.f;
    float u_[9][4];
    #pragma unroll
    for (int s = 0; s < 9; ++s){
        const int tf = s, tr = 8 - s;
        float xf = a2[tf], xr = a2[tr];
        {
            const float* W = L1F; const float* U = L1F + 8; const float* Bb = L1F + 24;
            float zi0 = fmaf(W[0], xf, fmaf(U[0],  hf0, fmaf(U[1],  hf1, Bb[0])));
            float zi1 = fmaf(W[1], xf, fmaf(U[2],  hf0, fmaf(U[3],  hf1, Bb[1])));
            float zf0 = fmaf(W[2], xf, fmaf(U[4],  hf0, fmaf(U[5],  hf1, Bb[2])));
            float zf1 = fmaf(W[3], xf, fmaf(U[6],  hf0, fmaf(U[7],  hf1, Bb[3])));
            float zg0 = fmaf(W[4], xf, fmaf(U[8],  hf0, fmaf(U[9],  hf1, Bb[4])));
            float zg1 = fmaf(W[5], xf, fmaf(U[10], hf0, fmaf(U[11], hf1, Bb[5])));
            float zo0 = fmaf(W[6], xf, fmaf(U[12], hf0, fmaf(U[13], hf1, Bb[6])));
            float zo1 = fmaf(W[7], xf, fmaf(U[14], hf0, fmaf(U[15], hf1, Bb[7])));
            hf0 = cellh(zi0, zf0, zg0, zo0, cf0);
            hf1 = cellh(zi1, zf1, zg1, zo1, cf1);
        }
        {
            const float* W = L1R; const float* U = L1R + 8; const float* Bb = L1R + 24;
            float zi0 = fmaf(W[0], xr, fmaf(U[0],  hr0, fmaf(U[1],  hr1, Bb[0])));
            float zi1 = fmaf(W[1], xr, fmaf(U[2],  hr0, fmaf(U[3],  hr1, Bb[1])));
            float zf0 = fmaf(W[2], xr, fmaf(U[4],  hr0, fmaf(U[5],  hr1, Bb[2])));
            float zf1 = fmaf(W[3], xr, fmaf(U[6],  hr0, fmaf(U[7],  hr1, Bb[3])));
            float zg0 = fmaf(W[4], xr, fmaf(U[8],  hr0, fmaf(U[9],  hr1, Bb[4])));
            float zg1 = fmaf(W[5], xr, fmaf(U[10], hr0, fmaf(U[11], hr1, Bb[5])));
            float zo0 = fmaf(W[6], xr, fmaf(U[12], hr0, fmaf(U[13], hr1, Bb[6])));
            float zo1 = fmaf(W[7], xr, fmaf(U[14], hr0, fmaf(U[15], hr1, Bb[7])));
            hr0 = cellh(zi0, zf0, zg0, zo0, cr0);
            hr1 = cellh(zi1, zf1, zg1, zo1, cr1);
        }
        u_[tf][0] = relu_(hf0);
        u_[tf][1] = relu_(hf1);
        u_[tr][2] = relu_(hr0);
        u_[tr][3] = relu_(hr1);
    }

    // ---- biLSTM layer 2 (scalar, both dirs) ----
    float h2f = 0.f, c2f = 0.f, h2r = 0.f, c2r = 0.f;
    float of[9], orr[9];
    #pragma unroll
    for (int s = 0; s < 9; ++s){
        const int tf = s, tr = 8 - s;
        {
            const float* W = L2F; const float* U = L2F + 16; const float* Bb = L2F + 20;
            float zi = fmaf(W[0],  u_[tf][0], fmaf(W[1],  u_[tf][1], fmaf(W[2],  u_[tf][2], fmaf(W[3],  u_[tf][3], fmaf(U[0], h2f, Bb[0])))));
            float zf = fmaf(W[4],  u_[tf][0], fmaf(W[5],  u_[tf][1], fmaf(W[6],  u_[tf][2], fmaf(W[7],  u_[tf][3], fmaf(U[1], h2f, Bb[1])))));
            float zg = fmaf(W[8],  u_[tf][0], fmaf(W[9],  u_[tf][1], fmaf(W[10], u_[tf][2], fmaf(W[11], u_[tf][3], fmaf(U[2], h2f, Bb[2])))));
            float zo = fmaf(W[12], u_[tf][0], fmaf(W[13], u_[tf][1], fmaf(W[14], u_[tf][2], fmaf(W[15], u_[tf][3], fmaf(U[3], h2f, Bb[3])))));
            h2f = cellh(zi, zf, zg, zo, c2f);
            of[tf] = h2f;
        }
        {
            const float* W = L2R; const float* U = L2R + 16; const float* Bb = L2R + 20;
            float zi = fmaf(W[0],  u_[tr][0], fmaf(W[1],  u_[tr][1], fmaf(W[2],  u_[tr][2], fmaf(W[3],  u_[tr][3], fmaf(U[0], h2r, Bb[0])))));
            float zf = fmaf(W[4],  u_[tr][0], fmaf(W[5],  u_[tr][1], fmaf(W[6],  u_[tr][2], fmaf(W[7],  u_[tr][3], fmaf(U[1], h2r, Bb[1])))));
            float zg = fmaf(W[8],  u_[tr][0], fmaf(W[9],  u_[tr][1], fmaf(W[10], u_[tr][2], fmaf(W[11], u_[tr][3], fmaf(U[2], h2r, Bb[2])))));
            float zo = fmaf(W[12], u_[tr][0], fmaf(W[13], u_[tr][1], fmaf(W[14], u_[tr][2], fmaf(W[15], u_[tr][3], fmaf(U[3], h2r, Bb[3])))));
            h2r = cellh(zi, zf, zg, zo, c2r);
            orr[tr] = h2r;
        }
    }

    float2* op = (float2*)(p.out + row * 18);
    #pragma unroll
    for (int t = 0; t < 9; ++t) op[t] = make_float2(of[t], orr[t]);
}

extern "C" void kernel_launch(void* const* d_in, const int* in_sizes, int n_in,
                              void* d_out, int out_size, void* d_ws, size_t ws_size,
                              hipStream_t stream)
{
    KParams p;
    p.x    = (const float*)d_in[0];
    p.emb  = (const float*)d_in[1];
    p.W1   = (const float*)d_in[2];
    p.b1   = (const float*)d_in[3];
    p.g1   = (const float*)d_in[4];
    p.be1  = (const float*)d_in[5];
    p.W2   = (const float*)d_in[6];
    p.b2   = (const float*)d_in[7];
    p.g2   = (const float*)d_in[8];
    p.be2  = (const float*)d_in[9];
    p.w1f  = (const float*)d_in[10];
    p.u1f  = (const float*)d_in[11];
    p.c1f  = (const float*)d_in[12];
    p.w1r  = (const float*)d_in[13];
    p.u1r  = (const float*)d_in[14];
    p.c1r  = (const float*)d_in[15];
    p.w2f  = (const float*)d_in[16];
    p.u2f  = (const float*)d_in[17];
    p.c2f  = (const float*)d_in[18];
    p.w2r  = (const float*)d_in[19];
    p.u2r  = (const float*)d_in[20];
    p.c2r  = (const float*)d_in[21];
    p.ws   = (float*)d_ws;
    p.out  = (float*)d_out;
    p.B    = in_sizes[0] / 8;

    int nb4 = (p.B + 1023) / 1024;
    if (nb4 > 1024) nb4 = 1024;       // grid-stride caps partial count at 1024
    p.nbp = nb4;

    bool use_ws = ws_size >= (size_t)(WS_Z2 + 9 * (size_t)p.B) * sizeof(float);
    int nb1 = (p.B + 255) / 256;

    k_moments<<<nb4, 256, 0, stream>>>(p.x, p.emb, p.ws + WS_PART1, p.B);
    kRed1<<<1, 1024, 0, stream>>>(p);
    if (use_ws) k_stats2<1><<<nb4, 256, 0, stream>>>(p);
    else        k_stats2<0><<<nb4, 256, 0, stream>>>(p);
    kPrep<<<1, 256, 0, stream>>>(p);
    if (use_ws) kB<1><<<nb1, 256, 0, stream>>>(p);
    else        kB<0><<<nb1, 256, 0, stream>>>(p);
}